// Round 8
// baseline (119.874 us; speedup 1.0000x reference)
//
#include <hip/hip_runtime.h>
#include <math.h>

// ---------------------------------------------------------------------------
// IrrepsToHessian, round 16.
//
// R15 post-mortem: removing ~1500 DS-cyc/wave changed NOTHING (46.5us both) ->
// DS-issue model falsified. No pipe >30%, Occupancy 17% -> LATENCY-bound at
// 2 blocks/CU. R16 attacks occupancy: LDS 78.3KB -> 44.1KB -> 3 blocks/CU.
//  - X2 LDS tile DELETED (-37.9KB): cart x2 read from global (config's 64
//    cols = contiguous 36KB slab, L1/L2-resident, idle VMEM pipe, 36
//    independent b128/lane).
//  - sMq overlaid on dead sTPWT region (new A->B barrier makes it safe).
//  - Mq as 9 planes [a][144]/wave: Phase B 9 conflict-free scalar writes;
//    cart 9 broadcast b128 per 4 c (324/wave). FP order per acc[a]
//    unchanged -> bit-identical output.
//  - out staging overlays dead pT slice (wave-local). 2 barriers.
// Phase A/B math verbatim from fused8 (proven). No ws.
// ---------------------------------------------------------------------------

#define NPATH 15

// ======================= compile-time Wigner machinery =====================
constexpr double cfact(int n){ double r = 1.0; for (int i = 2; i <= n; ++i) r *= (double)i; return r; }
constexpr double csqrt(double x){
  if (x <= 0.0) return 0.0;
  double g = x < 1.0 ? 1.0 : x;
  for (int i = 0; i < 64; ++i) g = 0.5*(g + x/g);
  return g;
}

constexpr double ccg(int j1,int m1,int j2,int m2,int j3,int m3){
  if (m3 != m1 + m2) return 0.0;
  int vmin = -j1 + j2 + m3;
  if (-j1 + m1 > vmin) vmin = -j1 + m1;
  if (0 > vmin) vmin = 0;
  int vmax = j2 + j3 + m1;
  if (j3 - j1 + j2 < vmax) vmax = j3 - j1 + j2;
  if (j3 + m3 < vmax) vmax = j3 + m3;
  double C = csqrt((2.0*j3+1.0)*cfact(j3+j1-j2)*cfact(j3-j1+j2)*cfact(j1+j2-j3)
                   *cfact(j3+m3)*cfact(j3-m3)
                   /(cfact(j1+j2+j3+1)*cfact(j1-m1)*cfact(j1+m1)*cfact(j2-m2)*cfact(j2+m2)));
  double S = 0.0;
  for (int v = vmin; v <= vmax; ++v){
    double term = cfact(j2+j3+m1-v)*cfact(j1-m1+v)
                /(cfact(v)*cfact(j3-j1+j2-v)*cfact(j3+m3-v)*cfact(v+j1-j2-m3));
    S += ((v + j2 + m2) & 1) ? -term : term;
  }
  return C * S;
}

struct QM { double re[5][5]; double im[5][5]; };
constexpr QM cbuild_q(int l){
  QM q{};
  double s = 1.0 / csqrt(2.0);
  for (int m = -l; m < 0; ++m){
    q.re[l+m][l-m] = s;
    q.im[l+m][l+m] = -s;
  }
  q.re[l][l] = 1.0;
  for (int m = 1; m <= l; ++m){
    double sg = (m & 1) ? -1.0 : 1.0;
    q.re[l+m][l+m] = sg * s;
    q.im[l+m][l-m] = sg * s;
  }
  if (l == 1){           // * (-i): (a+bi) -> (b, -a)
    for (int r = 0; r < 5; ++r)
      for (int c = 0; c < 5; ++c){
        double a = q.re[r][c], b = q.im[r][c];
        q.re[r][c] = b; q.im[r][c] = -a;
      }
  } else if (l == 2){    // * (-1)
    for (int r = 0; r < 5; ++r)
      for (int c = 0; c < 5; ++c){ q.re[r][c] = -q.re[r][c]; q.im[r][c] = -q.im[r][c]; }
  }
  return q;
}

struct CRP { double v[125]; };   // normalized real w3j, [(i*d2+j)*d3+m]
constexpr CRP make_cr(int l1, int l2, int l3){
  QM q1 = cbuild_q(l1), q2 = cbuild_q(l2), q3 = cbuild_q(l3);
  const int d1 = 2*l1+1, d2 = 2*l2+1, d3 = 2*l3+1;
  double CG[125] = {};
  for (int i = 0; i < d1; ++i)
    for (int k = 0; k < d2; ++k)
      for (int m = 0; m < d3; ++m)
        CG[(i*5 + k)*5 + m] = ccg(l1, i-l1, l2, k-l2, l3, m-l3);
  CRP o{};
  for (int j = 0; j < d1; ++j)
    for (int l = 0; l < d2; ++l)
      for (int n = 0; n < d3; ++n){
        double acc = 0.0;
        for (int i = 0; i < d1; ++i)
          for (int k = 0; k < d2; ++k)
            for (int m = 0; m < d3; ++m){
              double c = CG[(i*5 + k)*5 + m];
              if (c == 0.0) continue;
              double are = q1.re[i][j], aim = q1.im[i][j];
              double bre = q2.re[k][l], bim = q2.im[k][l];
              double tre = are*bre - aim*bim;
              double tim = are*bim + aim*bre;
              double cre = q3.re[m][n], cim = q3.im[m][n];
              acc += (tre*cre + tim*cim) * c;   // Re( q1 q2 conj(q3) CG )
            }
        o.v[(j*d2 + l)*d3 + n] = acc;
      }
  double s2 = 0.0;
  for (int e = 0; e < d1*d2*d3; ++e) s2 += o.v[e]*o.v[e];
  double inv = 1.0 / csqrt(s2);
  for (int e = 0; e < d1*d2*d3; ++e) o.v[e] *= inv;
  return o;
}

constexpr CRP CR0  = make_cr(0,0,0);
constexpr CRP CR1  = make_cr(1,1,0);
constexpr CRP CR2  = make_cr(2,2,0);
constexpr CRP CR3  = make_cr(0,1,1);
constexpr CRP CR4  = make_cr(1,0,1);
constexpr CRP CR5  = make_cr(1,1,1);
constexpr CRP CR6  = make_cr(1,2,1);
constexpr CRP CR7  = make_cr(2,1,1);
constexpr CRP CR8  = make_cr(2,2,1);
constexpr CRP CR9  = make_cr(0,2,2);
constexpr CRP CR10 = make_cr(2,0,2);
constexpr CRP CR11 = make_cr(1,1,2);
constexpr CRP CR12 = make_cr(1,2,2);
constexpr CRP CR13 = make_cr(2,1,2);
constexpr CRP CR14 = make_cr(2,2,2);

struct QCT { double v[81]; };    // QCART[lm][i*3+j]
constexpr QCT make_qc(){
  QCT q{};
  for (int lm = 0; lm < 9; ++lm){
    int l = (lm == 0) ? 0 : ((lm < 4) ? 1 : 2);
    int m = lm - l*l;
    const CRP& cr = (l == 0) ? CR1 : ((l == 1) ? CR5 : CR11);  // paths (1,1,l)
    double sc = csqrt(2.0*l + 1.0);
    for (int r = 0; r < 9; ++r)
      q.v[lm*9 + r] = cr.v[r*(2*l+1) + m] * sc;
  }
  return q;
}
constexpr QCT QCt = make_qc();

// wq layout: 189 rows, split b8 (a<8) + b1 (a==8)
struct WQT { float b8[189*8]; float b1[189]; };
constexpr WQT make_wq(){
  WQT t{};
  const CRP* crs[NPATH] = {&CR0,&CR1,&CR2,&CR3,&CR4,&CR5,&CR6,&CR7,&CR8,&CR9,
                           &CR10,&CR11,&CR12,&CR13,&CR14};
  const int L1[NPATH]   = {0,1,2,0,1,1,1,2,2,0,2,1,1,2,2};
  const int L2[NPATH]   = {0,1,2,1,0,1,2,1,2,2,0,1,2,1,2};
  const int LO[NPATH]   = {0,0,0,1,1,1,1,1,1,2,2,2,2,2,2};
  const int PROW[NPATH] = {0,1,10,35,38,41,50,65,80,105,110,115,124,139,164};
  const double AL[3] = { csqrt(1.0/768.0), csqrt(3.0/1536.0), csqrt(5.0/1536.0) };
  for (int p = 0; p < NPATH; ++p){
    const int d1 = 2*L1[p]+1, d2 = 2*L2[p]+1, d3 = 2*LO[p]+1, lo = LO[p];
    for (int i = 0; i < d1; ++i)
      for (int j = 0; j < d2; ++j)
        for (int a = 0; a < 9; ++a){
          double acc = 0.0;
          for (int m = 0; m < d3; ++m)
            acc += crs[p]->v[(i*d2 + j)*d3 + m] * QCt.v[(lo*lo + m)*9 + a];
          double val = AL[lo] * acc;
          int row = PROW[p] + i*d2 + j;
          if (a < 8) t.b8[row*8 + a] = (float)val;
          else       t.b1[row]       = (float)val;
        }
  }
  return t;
}
__constant__ WQT cWQ = make_wq();

// ======================= runtime tables ====================================
__constant__ int cP_L1[NPATH]   = {0,1,2,0,1,1,1,2,2,0,2,1,1,2,2};
__constant__ int cC2P[51] = {0, 1,1,1, 2,2,2,2,2, 3, 4,4,4, 5,5,5, 6,6,6,
                             7,7,7,7,7, 8,8,8,8,8, 9, 10,10,10,10,10,
                             11,11,11, 12,12,12, 13,13,13,13,13, 14,14,14,14,14};
__constant__ int cC2I[51] = {0, 0,1,2, 0,1,2,3,4, 0, 0,1,2, 0,1,2, 0,1,2,
                             0,1,2,3,4, 0,1,2,3,4, 0, 0,1,2,3,4,
                             0,1,2, 0,1,2, 0,1,2,3,4, 0,1,2,3,4};

// ---------------- LDS layout (floats) --------------------------------------
//   WQ8  [0,1512)  | WQ1 [1512,1704)
//   PT   [1704,4968)   4 x 816 per wave; out-staging overlays per-wave slice
//   OVR  [4968,10152)  Phase A: sTPWT (15x324, stride 20) = 4860
//                      Phase B/cart: sMq 4 x 1296 ([a][144] planes) = 5184
//   X1T  [10152,10920) 4 x 192
// U total 10920 fl = 43680 B (+ sCol 256B + sMeta 204B) -> 3 blocks/CU.
#define WQ8_OFF  0
#define WQ1_OFF  1512
#define PT_OFF   1704
#define OVR_OFF  4968
#define X1T_OFF  10152
#define U_SIZE   10920

// ACCP: one path's contribution to acc[9] (reads pT, sB8, sB1, v, j, D2)
#define ACCP(TOFF_, PROW_, D1_)                                              \
  { _Pragma("unroll")                                                        \
    for (int i = 0; i < (D1_); ++i){                                         \
      float tv = pT[((TOFF_) + i) * 16 + v];                                 \
      int row = (PROW_) + i * D2 + j;                                        \
      const float4 m0 = *(const float4*)&sB8[row * 8];                       \
      const float4 m1 = *(const float4*)&sB8[row * 8 + 4];                   \
      const float  m8 = sB1[row];                                            \
      acc[0] += tv*m0.x; acc[1] += tv*m0.y; acc[2] += tv*m0.z;               \
      acc[3] += tv*m0.w; acc[4] += tv*m1.x; acc[5] += tv*m1.y;               \
      acc[6] += tv*m1.z; acc[7] += tv*m1.w; acc[8] += tv*m8;                 \
    } }

// ---------------------------------------------------------------------------
__global__ __launch_bounds__(256, 3) void fused9_kernel(
    const float* __restrict__ feats,    // (4096, 144)
    const int*   __restrict__ layout,   // (E, 2)
    const float* __restrict__ tpw,      // (15, 16, 16)
    float*       __restrict__ out)      // (E, 9)
{
  __shared__ __align__(16) float U[U_SIZE];
  __shared__ int sCol[64];
  __shared__ int sMeta[51];

  const int tid  = threadIdx.x;
  const int wave = tid >> 6;
  const int lane = tid & 63;
  const int rwBase = blockIdx.x * 4;             // 4 row-blocks, same config
  const int rw = rwBase + wave;

  float* sB8   = U + WQ8_OFF;
  float* sB1   = U + WQ1_OFF;
  float* sTPWT = U + OVR_OFF;

  // ---- stage shared tables (coalesced / tiny) ----
  for (int o = tid; o < 1512; o += 256) sB8[o] = cWQ.b8[o];
  if (tid < 189) sB1[tid] = cWQ.b1[tid];
  // tpw transposed: sTPWT[p*324 + v*20 + u] = tpw[p*256 + u*16 + v]
  for (int e = tid; e < 3840; e += 256){
    int p = e >> 8, r = e & 255, u = r >> 4, v = r & 15;
    sTPWT[p * 324 + v * 20 + u] = tpw[e];
  }
  if (tid < 51){
    int p = cC2P[tid], i = cC2I[tid], l1 = cP_L1[p];
    int xb = (l1 == 0) ? 0 : ((l1 == 1) ? 16 + i * 20 : 80 + i * 20);
    sMeta[tid] = xb | ((p * 324) << 16);
  }
  if (tid >= 192)                                // the config's 64 column nodes
    sCol[tid - 192] = layout[2 * ((size_t)rwBase * 64 + (tid - 192)) + 1];

  // ---- stage x1 TRANSPOSED per wave: l0 [0,16) | l1 rows 20 @16 | l2 @80 ----
  {
    int rn = layout[2 * (rw * 64)];
    rn = __builtin_amdgcn_readfirstlane(rn);
    const float* g = feats + (size_t)rn * 144;
    float* xt = U + X1T_OFF + wave * 192;
    if (lane < 16) xt[lane] = g[lane];                               // l=0
    if (lane < 48){ int i = lane >> 4, u = lane & 15;                // l=1
      xt[16 + i * 20 + u] = g[16 + u * 3 + i]; }
    { int i = lane >> 4, u = lane & 15;                              // l=2 i<4
      xt[80 + i * 20 + u] = g[64 + u * 5 + i]; }
    if (lane < 16) xt[160 + lane] = g[64 + lane * 5 + 4];            // l=2 i=4
  }
  __syncthreads();                                                   // B1

  // ---- Phase A: t[c][v], 8x ds_read_b128 per c (same u-order, identical) --
  float* pT = U + PT_OFF + wave * 816;
  {
    const int v  = lane & 15;
    const int cq = lane >> 4;
    const float* xw = U + X1T_OFF + wave * 192;
    #pragma unroll
    for (int it = 0; it < 13; ++it){
      int c = cq + it * 4;
      if (c < 51){
        int md = sMeta[c];
        const float* xb = xw + (md & 0xffff);
        const float* wb = sTPWT + (md >> 16) + v * 20;
        float s = 0.f;
        #pragma unroll
        for (int u4 = 0; u4 < 4; ++u4){
          float4 xv = *(const float4*)(xb + u4 * 4);
          float4 wv = *(const float4*)(wb + u4 * 4);
          s += xv.x * wv.x; s += xv.y * wv.y;
          s += xv.z * wv.z; s += xv.w * wv.w;
        }
        pT[c * 16 + v] = s;
      }
    }
  }
  __syncthreads();   // B2: all waves done reading sTPWT -> sMq may overlay it

  // ---- Phase B: Mq -> sMq planes [a][144] per wave (math verbatim) ----
  float* pMq = U + OVR_OFF + wave * 1296;
  for (int rnd = 0; rnd < 3; ++rnd){
    int c = lane + rnd * 64;
    if (c >= 144) break;
    float acc[9];
    #pragma unroll
    for (int a = 0; a < 9; ++a) acc[a] = 0.f;
    if (c < 16){                    // l2 = 0 : paths 0,4,10
      const int v = c, j = 0;
      const int D2 = 1;
      ACCP(0,  0,   1)
      ACCP(10, 38,  3)
      ACCP(30, 110, 5)
    } else if (c < 64){             // l2 = 1 : paths 1,3,5,7,11,13
      const int v = (c - 16) / 3, j = (c - 16) % 3;
      const int D2 = 3;
      ACCP(1,  1,   3)
      ACCP(9,  35,  1)
      ACCP(13, 41,  3)
      ACCP(19, 65,  5)
      ACCP(35, 115, 3)
      ACCP(41, 139, 5)
    } else {                        // l2 = 2 : paths 2,6,8,9,12,14
      const int v = (c - 64) / 5, j = (c - 64) % 5;
      const int D2 = 5;
      ACCP(4,  10,  5)
      ACCP(16, 50,  3)
      ACCP(24, 80,  5)
      ACCP(29, 105, 1)
      ACCP(38, 124, 3)
      ACCP(46, 164, 5)
    }
    #pragma unroll
    for (int a = 0; a < 9; ++a) pMq[a * 144 + c] = acc[a];  // conflict-free
  }
  // no barrier: cart reads ONLY this wave's pMq (wave-local lgkmcnt order)

  // ---- cart: acc[a] = sum_c x2[j][c] * Mq[c][a] ----
  // x2 from GLOBAL (per-lane row, L1/L2-resident, idle VMEM pipe);
  // Mq as 9 broadcast b128 per 4 c. FP order per acc[a] = c ascending,
  // identical to fused8.
  {
    const int myCol = sCol[lane];
    const float* xg = feats + (size_t)myCol * 144;
    float acc[9];
    #pragma unroll
    for (int a = 0; a < 9; ++a) acc[a] = 0.f;

    #pragma unroll 6
    for (int c4 = 0; c4 < 36; ++c4){
      float4 xv = *(const float4*)(xg + c4 * 4);
      #pragma unroll
      for (int a = 0; a < 9; ++a){
        const float4 m = *(const float4*)&pMq[a * 144 + c4 * 4];
        acc[a] += xv.x * m.x;
        acc[a] += xv.y * m.y;
        acc[a] += xv.z * m.z;
        acc[a] += xv.w * m.w;
      }
    }

    // ---- coalesced store via LDS staging (wave-local dead pT slice) ----
    float* pO = U + PT_OFF + wave * 816;
    #pragma unroll
    for (int a = 0; a < 9; ++a) pO[lane * 9 + a] = acc[a];
    float* ob = out + (size_t)rw * 576;
    #pragma unroll
    for (int r = 0; r < 3; ++r){
      int idx = lane + r * 64;                   // float4 index 0..143
      if (idx < 144){
        float4 vv = *(const float4*)(pO + idx * 4);
        *(float4*)(ob + idx * 4) = vv;
      }
    }
  }
}

// ---------------------------------------------------------------------------
// sym_tiled: 16x16 cell tile-pairs through LDS; fully coalesced; each element
// read+written exactly once. Block = (config b, tile-pair tp), 256 threads.
// ---------------------------------------------------------------------------
__global__ __launch_bounds__(256) void sym_tiled(float* __restrict__ out){
  __shared__ float sA[16 * 145];
  __shared__ float sB[16 * 145];
  const int tid = threadIdx.x;
  const int b  = blockIdx.x / 10;
  const int tp = blockIdx.x - b * 10;
  const int TI[10] = {0,0,0,0,1,1,1,2,2,3};
  const int TJ[10] = {0,1,2,3,1,2,3,2,3,3};
  const int ti = TI[tp], tj = TJ[tp];
  const bool diag = (ti == tj);
  const size_t cfgBase = (size_t)b * 4096 * 9;

  for (int idx = tid; idx < 2304; idx += 256){
    int r = idx / 144, off = idx - r * 144;
    sA[r * 145 + off] = out[cfgBase + ((size_t)(ti*16 + r) * 64 + tj*16) * 9 + off];
  }
  if (!diag){
    for (int idx = tid; idx < 2304; idx += 256){
      int r = idx / 144, off = idx - r * 144;
      sB[r * 145 + off] = out[cfgBase + ((size_t)(tj*16 + r) * 64 + ti*16) * 9 + off];
    }
  }
  __syncthreads();

  const int di = tid >> 4, dj = tid & 15;
  const float* A = sA;
  const float* B = diag ? sA : sB;
  float oa[9], ob[9];
  #pragma unroll
  for (int a = 0; a < 3; ++a)
    #pragma unroll
    for (int d = 0; d < 3; ++d){
      oa[a*3+d] = 0.5f * (A[di*145 + dj*9 + a*3+d] + B[dj*145 + di*9 + d*3+a]);
      if (!diag)
        ob[a*3+d] = 0.5f * (B[di*145 + dj*9 + a*3+d] + A[dj*145 + di*9 + d*3+a]);
    }
  __syncthreads();

  #pragma unroll
  for (int r9 = 0; r9 < 9; ++r9) sA[di*145 + dj*9 + r9] = oa[r9];
  if (!diag){
    #pragma unroll
    for (int r9 = 0; r9 < 9; ++r9) sB[di*145 + dj*9 + r9] = ob[r9];
  }
  __syncthreads();

  for (int idx = tid; idx < 2304; idx += 256){
    int r = idx / 144, off = idx - r * 144;
    out[cfgBase + ((size_t)(ti*16 + r) * 64 + tj*16) * 9 + off] = sA[r * 145 + off];
  }
  if (!diag){
    for (int idx = tid; idx < 2304; idx += 256){
      int r = idx / 144, off = idx - r * 144;
      out[cfgBase + ((size_t)(tj*16 + r) * 64 + ti*16) * 9 + off] = sB[r * 145 + off];
    }
  }
}

// ---------------------------------------------------------------------------
extern "C" void kernel_launch(void* const* d_in, const int* in_sizes, int n_in,
                              void* d_out, int out_size, void* d_ws, size_t ws_size,
                              hipStream_t stream) {
  const float* feats  = (const float*)d_in[0];   // (4096, 144)
  const int*   layout = (const int*)  d_in[1];   // (E, 2)
  const float* tpw    = (const float*)d_in[2];   // (15, 16, 16)
  float* out = (float*)d_out;
  (void)d_ws; (void)ws_size; (void)n_in; (void)out_size;

  const int E = in_sizes[1] / 2;                 // 262144
  const int R = E / 64;                          // 4096 row-blocks
  const int B = E / 4096;                        // 64 configs

  fused9_kernel<<<R / 4, 256, 0, stream>>>(feats, layout, tpw, out);
  sym_tiled<<<B * 10, 256, 0, stream>>>(out);
}

// Round 9
// 118.992 us; speedup vs baseline: 1.0074x; 1.0074x over previous
//
#include <hip/hip_runtime.h>
#include <math.h>

// ---------------------------------------------------------------------------
// IrrepsToHessian, round 17.
//
// Ledger: DS-count (R15), occupancy (R16), Mq transport (R9-R13), conflicts
// (R14) all falsified as the fused kernel's 46-55us bottleneck; all pipes
// <30%, models predict ~20us. Last untested axis: CODE SIZE. fused8 is
// ~2500 straight-line instrs (~20KB): 51 unrolled ACCP bodies + 36-deep
// cart + 13-deep Phase A, each executed ONCE per wave -> no I$ reuse, L1I
// thrash. Fetch stalls are invisible to every counter collected.
//
// R17 (fused10) = fused8 with compact code, nothing else changed:
//  - Phase B: data-driven loop over __constant__ item tables (toff,row
//    packed; same order as ACCP macros -> bit-identical FP).
//  - Phase A / cart / x2-staging: #pragma unroll 2 instead of full unroll.
//  - Layouts, barriers, LDS (78.3KB, 2 blocks/CU), math: identical.
// ---------------------------------------------------------------------------

#define NPATH 15

// ======================= compile-time Wigner machinery =====================
constexpr double cfact(int n){ double r = 1.0; for (int i = 2; i <= n; ++i) r *= (double)i; return r; }
constexpr double csqrt(double x){
  if (x <= 0.0) return 0.0;
  double g = x < 1.0 ? 1.0 : x;
  for (int i = 0; i < 64; ++i) g = 0.5*(g + x/g);
  return g;
}

constexpr double ccg(int j1,int m1,int j2,int m2,int j3,int m3){
  if (m3 != m1 + m2) return 0.0;
  int vmin = -j1 + j2 + m3;
  if (-j1 + m1 > vmin) vmin = -j1 + m1;
  if (0 > vmin) vmin = 0;
  int vmax = j2 + j3 + m1;
  if (j3 - j1 + j2 < vmax) vmax = j3 - j1 + j2;
  if (j3 + m3 < vmax) vmax = j3 + m3;
  double C = csqrt((2.0*j3+1.0)*cfact(j3+j1-j2)*cfact(j3-j1+j2)*cfact(j1+j2-j3)
                   *cfact(j3+m3)*cfact(j3-m3)
                   /(cfact(j1+j2+j3+1)*cfact(j1-m1)*cfact(j1+m1)*cfact(j2-m2)*cfact(j2+m2)));
  double S = 0.0;
  for (int v = vmin; v <= vmax; ++v){
    double term = cfact(j2+j3+m1-v)*cfact(j1-m1+v)
                /(cfact(v)*cfact(j3-j1+j2-v)*cfact(j3+m3-v)*cfact(v+j1-j2-m3));
    S += ((v + j2 + m2) & 1) ? -term : term;
  }
  return C * S;
}

struct QM { double re[5][5]; double im[5][5]; };
constexpr QM cbuild_q(int l){
  QM q{};
  double s = 1.0 / csqrt(2.0);
  for (int m = -l; m < 0; ++m){
    q.re[l+m][l-m] = s;
    q.im[l+m][l+m] = -s;
  }
  q.re[l][l] = 1.0;
  for (int m = 1; m <= l; ++m){
    double sg = (m & 1) ? -1.0 : 1.0;
    q.re[l+m][l+m] = sg * s;
    q.im[l+m][l-m] = sg * s;
  }
  if (l == 1){           // * (-i): (a+bi) -> (b, -a)
    for (int r = 0; r < 5; ++r)
      for (int c = 0; c < 5; ++c){
        double a = q.re[r][c], b = q.im[r][c];
        q.re[r][c] = b; q.im[r][c] = -a;
      }
  } else if (l == 2){    // * (-1)
    for (int r = 0; r < 5; ++r)
      for (int c = 0; c < 5; ++c){ q.re[r][c] = -q.re[r][c]; q.im[r][c] = -q.im[r][c]; }
  }
  return q;
}

struct CRP { double v[125]; };   // normalized real w3j, [(i*d2+j)*d3+m]
constexpr CRP make_cr(int l1, int l2, int l3){
  QM q1 = cbuild_q(l1), q2 = cbuild_q(l2), q3 = cbuild_q(l3);
  const int d1 = 2*l1+1, d2 = 2*l2+1, d3 = 2*l3+1;
  double CG[125] = {};
  for (int i = 0; i < d1; ++i)
    for (int k = 0; k < d2; ++k)
      for (int m = 0; m < d3; ++m)
        CG[(i*5 + k)*5 + m] = ccg(l1, i-l1, l2, k-l2, l3, m-l3);
  CRP o{};
  for (int j = 0; j < d1; ++j)
    for (int l = 0; l < d2; ++l)
      for (int n = 0; n < d3; ++n){
        double acc = 0.0;
        for (int i = 0; i < d1; ++i)
          for (int k = 0; k < d2; ++k)
            for (int m = 0; m < d3; ++m){
              double c = CG[(i*5 + k)*5 + m];
              if (c == 0.0) continue;
              double are = q1.re[i][j], aim = q1.im[i][j];
              double bre = q2.re[k][l], bim = q2.im[k][l];
              double tre = are*bre - aim*bim;
              double tim = are*bim + aim*bre;
              double cre = q3.re[m][n], cim = q3.im[m][n];
              acc += (tre*cre + tim*cim) * c;   // Re( q1 q2 conj(q3) CG )
            }
        o.v[(j*d2 + l)*d3 + n] = acc;
      }
  double s2 = 0.0;
  for (int e = 0; e < d1*d2*d3; ++e) s2 += o.v[e]*o.v[e];
  double inv = 1.0 / csqrt(s2);
  for (int e = 0; e < d1*d2*d3; ++e) o.v[e] *= inv;
  return o;
}

constexpr CRP CR0  = make_cr(0,0,0);
constexpr CRP CR1  = make_cr(1,1,0);
constexpr CRP CR2  = make_cr(2,2,0);
constexpr CRP CR3  = make_cr(0,1,1);
constexpr CRP CR4  = make_cr(1,0,1);
constexpr CRP CR5  = make_cr(1,1,1);
constexpr CRP CR6  = make_cr(1,2,1);
constexpr CRP CR7  = make_cr(2,1,1);
constexpr CRP CR8  = make_cr(2,2,1);
constexpr CRP CR9  = make_cr(0,2,2);
constexpr CRP CR10 = make_cr(2,0,2);
constexpr CRP CR11 = make_cr(1,1,2);
constexpr CRP CR12 = make_cr(1,2,2);
constexpr CRP CR13 = make_cr(2,1,2);
constexpr CRP CR14 = make_cr(2,2,2);

struct QCT { double v[81]; };    // QCART[lm][i*3+j]
constexpr QCT make_qc(){
  QCT q{};
  for (int lm = 0; lm < 9; ++lm){
    int l = (lm == 0) ? 0 : ((lm < 4) ? 1 : 2);
    int m = lm - l*l;
    const CRP& cr = (l == 0) ? CR1 : ((l == 1) ? CR5 : CR11);  // paths (1,1,l)
    double sc = csqrt(2.0*l + 1.0);
    for (int r = 0; r < 9; ++r)
      q.v[lm*9 + r] = cr.v[r*(2*l+1) + m] * sc;
  }
  return q;
}
constexpr QCT QCt = make_qc();

// wq layout: 189 rows, split b8 (a<8) + b1 (a==8)
struct WQT { float b8[189*8]; float b1[189]; };
constexpr WQT make_wq(){
  WQT t{};
  const CRP* crs[NPATH] = {&CR0,&CR1,&CR2,&CR3,&CR4,&CR5,&CR6,&CR7,&CR8,&CR9,
                           &CR10,&CR11,&CR12,&CR13,&CR14};
  const int L1[NPATH]   = {0,1,2,0,1,1,1,2,2,0,2,1,1,2,2};
  const int L2[NPATH]   = {0,1,2,1,0,1,2,1,2,2,0,1,2,1,2};
  const int LO[NPATH]   = {0,0,0,1,1,1,1,1,1,2,2,2,2,2,2};
  const int PROW[NPATH] = {0,1,10,35,38,41,50,65,80,105,110,115,124,139,164};
  const double AL[3] = { csqrt(1.0/768.0), csqrt(3.0/1536.0), csqrt(5.0/1536.0) };
  for (int p = 0; p < NPATH; ++p){
    const int d1 = 2*L1[p]+1, d2 = 2*L2[p]+1, d3 = 2*LO[p]+1, lo = LO[p];
    for (int i = 0; i < d1; ++i)
      for (int j = 0; j < d2; ++j)
        for (int a = 0; a < 9; ++a){
          double acc = 0.0;
          for (int m = 0; m < d3; ++m)
            acc += crs[p]->v[(i*d2 + j)*d3 + m] * QCt.v[(lo*lo + m)*9 + a];
          double val = AL[lo] * acc;
          int row = PROW[p] + i*d2 + j;
          if (a < 8) t.b8[row*8 + a] = (float)val;
          else       t.b1[row]       = (float)val;
        }
  }
  return t;
}
__constant__ WQT cWQ = make_wq();

// ======================= runtime tables ====================================
__constant__ int cP_L1[NPATH]   = {0,1,2,0,1,1,1,2,2,0,2,1,1,2,2};
__constant__ int cC2P[51] = {0, 1,1,1, 2,2,2,2,2, 3, 4,4,4, 5,5,5, 6,6,6,
                             7,7,7,7,7, 8,8,8,8,8, 9, 10,10,10,10,10,
                             11,11,11, 12,12,12, 13,13,13,13,13, 14,14,14,14,14};
__constant__ int cC2I[51] = {0, 0,1,2, 0,1,2,3,4, 0, 0,1,2, 0,1,2, 0,1,2,
                             0,1,2,3,4, 0,1,2,3,4, 0, 0,1,2,3,4,
                             0,1,2, 0,1,2, 0,1,2,3,4, 0,1,2,3,4};

// Phase-B item tables: (toff<<8)|row per (path,i), SAME order as the old
// ACCP macro expansion -> bit-identical accumulation.
__constant__ int cIT0[9]  = {                       // l2=0 (D2=1)
  (0<<8)|0,
  (10<<8)|38,(11<<8)|39,(12<<8)|40,
  (30<<8)|110,(31<<8)|111,(32<<8)|112,(33<<8)|113,(34<<8)|114};
__constant__ int cIT1[20] = {                       // l2=1 (D2=3)
  (1<<8)|1,(2<<8)|4,(3<<8)|7,
  (9<<8)|35,
  (13<<8)|41,(14<<8)|44,(15<<8)|47,
  (19<<8)|65,(20<<8)|68,(21<<8)|71,(22<<8)|74,(23<<8)|77,
  (35<<8)|115,(36<<8)|118,(37<<8)|121,
  (41<<8)|139,(42<<8)|142,(43<<8)|145,(44<<8)|148,(45<<8)|151};
__constant__ int cIT2[22] = {                       // l2=2 (D2=5)
  (4<<8)|10,(5<<8)|15,(6<<8)|20,(7<<8)|25,(8<<8)|30,
  (16<<8)|50,(17<<8)|55,(18<<8)|60,
  (24<<8)|80,(25<<8)|85,(26<<8)|90,(27<<8)|95,(28<<8)|100,
  (29<<8)|105,
  (38<<8)|124,(39<<8)|129,(40<<8)|134,
  (46<<8)|164,(47<<8)|169,(48<<8)|174,(49<<8)|179,(50<<8)|184};

// Phase-B loop body (reads pT, sB8, sB1, v, j, md from scope)
#define BDY {                                                                \
  float tv = pT[(md >> 8) * 16 + v];                                         \
  int row = (md & 255) + j;                                                  \
  const float4 m0 = *(const float4*)&sB8[row * 8];                           \
  const float4 m1 = *(const float4*)&sB8[row * 8 + 4];                       \
  const float  m8 = sB1[row];                                                \
  acc[0] += tv*m0.x; acc[1] += tv*m0.y; acc[2] += tv*m0.z;                   \
  acc[3] += tv*m0.w; acc[4] += tv*m1.x; acc[5] += tv*m1.y;                   \
  acc[6] += tv*m1.z; acc[7] += tv*m1.w; acc[8] += tv*m8; }

// ---------------------------------------------------------------------------
// fused10_kernel: identical structure/layout to fused8; compact code.
//   phase A/B: [0,1512)=sB8 | [1512,1704)=sB1 | [1704,4968)=pT(4x816)
//              | [4968,9828)=sTPWT(15x324, stride 20)
//   cart:      [0,9472)=sX2R(64 x 148 pad) | [9472,11776)=sOut(4x576)
// Static: 78.3KB -> 2 blocks/CU.
// ---------------------------------------------------------------------------
__global__ __launch_bounds__(256, 2) void fused10_kernel(
    const float* __restrict__ feats,    // (4096, 144)
    const int*   __restrict__ layout,   // (E, 2)
    const float* __restrict__ tpw,      // (15, 16, 16)
    float*       __restrict__ out)      // (E, 9)
{
  __shared__ __align__(16) float U[11776];
  __shared__ __align__(16) float sMq[4][1728];   // Mq [c][12] per wave
  __shared__ __align__(16) float sX1T[4][192];
  __shared__ int sCol[64];
  __shared__ int sMeta[51];

  const int tid  = threadIdx.x;
  const int wave = tid >> 6;
  const int lane = tid & 63;
  const int rwBase = blockIdx.x * 4;             // 4 row-blocks, same config
  const int rw = rwBase + wave;

  float* sB8   = U;
  float* sB1   = U + 1512;
  float* sTPWT = U + 4968;

  // ---- stage shared tables (coalesced / tiny) ----
  for (int o = tid; o < 1512; o += 256) sB8[o] = cWQ.b8[o];
  if (tid < 189) sB1[tid] = cWQ.b1[tid];
  // tpw transposed: sTPWT[p*324 + v*20 + u] = tpw[p*256 + u*16 + v]
  for (int e = tid; e < 3840; e += 256){
    int p = e >> 8, r = e & 255, u = r >> 4, v = r & 15;
    sTPWT[p * 324 + v * 20 + u] = tpw[e];
  }
  if (tid < 51){
    int p = cC2P[tid], i = cC2I[tid], l1 = cP_L1[p];
    int xb = (l1 == 0) ? 0 : ((l1 == 1) ? 16 + i * 20 : 80 + i * 20);
    sMeta[tid] = xb | ((p * 324) << 16);
  }
  if (tid >= 192)                                // the config's 64 column nodes
    sCol[tid - 192] = layout[2 * ((size_t)rwBase * 64 + (tid - 192)) + 1];

  // ---- stage x1 TRANSPOSED per wave: l0 [0,16) | l1 rows 20 @16 | l2 @80 ----
  {
    int rn = layout[2 * (rw * 64)];
    rn = __builtin_amdgcn_readfirstlane(rn);
    const float* g = feats + (size_t)rn * 144;
    float* xt = sX1T[wave];
    if (lane < 16) xt[lane] = g[lane];                               // l=0
    if (lane < 48){ int i = lane >> 4, u = lane & 15;                // l=1
      xt[16 + i * 20 + u] = g[16 + u * 3 + i]; }
    { int i = lane >> 4, u = lane & 15;                              // l=2 i<4
      xt[80 + i * 20 + u] = g[64 + u * 5 + i]; }
    if (lane < 16) xt[160 + lane] = g[64 + lane * 5 + 4];            // l=2 i=4
  }
  __syncthreads();

  // ---- Phase A: t[c][v], 8x ds_read_b128 per c (rolled, unroll 2) ----
  float* pT = U + 1704 + wave * 816;
  {
    const int v  = lane & 15;
    const int cq = lane >> 4;
    const float* xw = sX1T[wave];
    #pragma unroll 2
    for (int it = 0; it < 13; ++it){
      int c = cq + it * 4;
      if (c < 51){
        int md = sMeta[c];
        const float* xb = xw + (md & 0xffff);
        const float* wb = sTPWT + (md >> 16) + v * 20;
        float s = 0.f;
        #pragma unroll
        for (int u4 = 0; u4 < 4; ++u4){
          float4 xv = *(const float4*)(xb + u4 * 4);
          float4 wv = *(const float4*)(wb + u4 * 4);
          s += xv.x * wv.x; s += xv.y * wv.y;
          s += xv.z * wv.z; s += xv.w * wv.w;
        }
        pT[c * 16 + v] = s;
      }
    }
  }
  // no barrier: pT wave-local; sMq region disjoint from staged tables

  // ---- Phase B: Mq[c][a] -> sMq[wave] (data-driven loops, same FP order) --
  float* pM = sMq[wave];
  for (int rnd = 0; rnd < 3; ++rnd){
    int c = lane + rnd * 64;
    if (c >= 144) break;
    float acc[9];
    #pragma unroll
    for (int a = 0; a < 9; ++a) acc[a] = 0.f;
    if (c < 16){                    // l2 = 0 : paths 0,4,10
      const int v = c, j = 0;
      #pragma unroll 2
      for (int it = 0; it < 9; ++it){ int md = cIT0[it]; BDY }
    } else if (c < 64){             // l2 = 1 : paths 1,3,5,7,11,13
      const int v = (c - 16) / 3, j = (c - 16) % 3;
      #pragma unroll 2
      for (int it = 0; it < 20; ++it){ int md = cIT1[it]; BDY }
    } else {                        // l2 = 2 : paths 2,6,8,9,12,14
      const int v = (c - 64) / 5, j = (c - 64) % 5;
      #pragma unroll 2
      for (int it = 0; it < 22; ++it){ int md = cIT2[it]; BDY }
    }
    *(float4*)&pM[c * 12]     = make_float4(acc[0], acc[1], acc[2], acc[3]);
    *(float4*)&pM[c * 12 + 4] = make_float4(acc[4], acc[5], acc[6], acc[7]);
    pM[c * 12 + 8] = acc[8];
  }
  __syncthreads();   // all waves done reading sB8/sB1/pT before U is overlaid

  // ---- stage X2 row-major pad-148 (rolled, unroll 2) ----
  float* sX2R = U;
  #pragma unroll 2
  for (int k = 0; k < 9; ++k){
    int q = k * 256 + tid;                       // 0..2303 float4 tasks
    int j = q / 36, c4 = q - j * 36;
    const float4 xv = *(const float4*)(feats + (size_t)sCol[j] * 144 + c4 * 4);
    *(float4*)(sX2R + j * 148 + c4 * 4) = xv;
  }
  __syncthreads();

  // ---- cart (rolled, unroll 2): acc[a] = sum_c x2[j][c] * Mq[c][a] ----
  const float* xrow = sX2R + lane * 148;
  float acc[9];
  #pragma unroll
  for (int a = 0; a < 9; ++a) acc[a] = 0.f;

  #pragma unroll 2
  for (int c4 = 0; c4 < 36; ++c4){
    float4 xv = *(const float4*)(xrow + c4 * 4);
    #pragma unroll
    for (int r = 0; r < 4; ++r){
      int c = c4 * 4 + r;
      float xs = (r == 0) ? xv.x : ((r == 1) ? xv.y : ((r == 2) ? xv.z : xv.w));
      const float4 m0 = *(const float4*)&pM[c * 12];
      const float4 m1 = *(const float4*)&pM[c * 12 + 4];
      const float  m8 = pM[c * 12 + 8];
      acc[0] += xs * m0.x; acc[1] += xs * m0.y; acc[2] += xs * m0.z;
      acc[3] += xs * m0.w; acc[4] += xs * m1.x; acc[5] += xs * m1.y;
      acc[6] += xs * m1.z; acc[7] += xs * m1.w; acc[8] += xs * m8;
    }
  }

  // ---- coalesced store via LDS staging (wave-local region of U) ----
  float* pO = U + 9472 + wave * 576;
  #pragma unroll
  for (int a = 0; a < 9; ++a) pO[lane * 9 + a] = acc[a];
  float* ob = out + (size_t)rw * 576;
  #pragma unroll
  for (int r = 0; r < 3; ++r){
    int idx = lane + r * 64;                     // float4 index 0..143
    if (idx < 144){
      float4 vv = *(const float4*)(pO + idx * 4);
      *(float4*)(ob + idx * 4) = vv;
    }
  }
}

// ---------------------------------------------------------------------------
// sym_tiled: 16x16 cell tile-pairs through LDS; fully coalesced; each element
// read+written exactly once. Block = (config b, tile-pair tp), 256 threads.
// ---------------------------------------------------------------------------
__global__ __launch_bounds__(256) void sym_tiled(float* __restrict__ out){
  __shared__ float sA[16 * 145];
  __shared__ float sB[16 * 145];
  const int tid = threadIdx.x;
  const int b  = blockIdx.x / 10;
  const int tp = blockIdx.x - b * 10;
  const int TI[10] = {0,0,0,0,1,1,1,2,2,3};
  const int TJ[10] = {0,1,2,3,1,2,3,2,3,3};
  const int ti = TI[tp], tj = TJ[tp];
  const bool diag = (ti == tj);
  const size_t cfgBase = (size_t)b * 4096 * 9;

  for (int idx = tid; idx < 2304; idx += 256){
    int r = idx / 144, off = idx - r * 144;
    sA[r * 145 + off] = out[cfgBase + ((size_t)(ti*16 + r) * 64 + tj*16) * 9 + off];
  }
  if (!diag){
    for (int idx = tid; idx < 2304; idx += 256){
      int r = idx / 144, off = idx - r * 144;
      sB[r * 145 + off] = out[cfgBase + ((size_t)(tj*16 + r) * 64 + ti*16) * 9 + off];
    }
  }
  __syncthreads();

  const int di = tid >> 4, dj = tid & 15;
  const float* A = sA;
  const float* B = diag ? sA : sB;
  float oa[9], ob[9];
  #pragma unroll
  for (int a = 0; a < 3; ++a)
    #pragma unroll
    for (int d = 0; d < 3; ++d){
      oa[a*3+d] = 0.5f * (A[di*145 + dj*9 + a*3+d] + B[dj*145 + di*9 + d*3+a]);
      if (!diag)
        ob[a*3+d] = 0.5f * (B[di*145 + dj*9 + a*3+d] + A[dj*145 + di*9 + d*3+a]);
    }
  __syncthreads();

  #pragma unroll
  for (int r9 = 0; r9 < 9; ++r9) sA[di*145 + dj*9 + r9] = oa[r9];
  if (!diag){
    #pragma unroll
    for (int r9 = 0; r9 < 9; ++r9) sB[di*145 + dj*9 + r9] = ob[r9];
  }
  __syncthreads();

  for (int idx = tid; idx < 2304; idx += 256){
    int r = idx / 144, off = idx - r * 144;
    out[cfgBase + ((size_t)(ti*16 + r) * 64 + tj*16) * 9 + off] = sA[r * 145 + off];
  }
  if (!diag){
    for (int idx = tid; idx < 2304; idx += 256){
      int r = idx / 144, off = idx - r * 144;
      out[cfgBase + ((size_t)(tj*16 + r) * 64 + ti*16) * 9 + off] = sB[r * 145 + off];
    }
  }
}

// ---------------------------------------------------------------------------
extern "C" void kernel_launch(void* const* d_in, const int* in_sizes, int n_in,
                              void* d_out, int out_size, void* d_ws, size_t ws_size,
                              hipStream_t stream) {
  const float* feats  = (const float*)d_in[0];   // (4096, 144)
  const int*   layout = (const int*)  d_in[1];   // (E, 2)
  const float* tpw    = (const float*)d_in[2];   // (15, 16, 16)
  float* out = (float*)d_out;
  (void)d_ws; (void)ws_size; (void)n_in; (void)out_size;

  const int E = in_sizes[1] / 2;                 // 262144
  const int R = E / 64;                          // 4096 row-blocks
  const int B = E / 4096;                        // 64 configs

  fused10_kernel<<<R / 4, 256, 0, stream>>>(feats, layout, tpw, out);
  sym_tiled<<<B * 10, 256, 0, stream>>>(out);
}